// Round 14
// baseline (240.824 us; speedup 1.0000x reference)
//
#include <hip/hip_runtime.h>
#include <hip/hip_bf16.h>
#include <stdint.h>

#define NROWS   65536
#define EPS     1e-5f
#define BM      32
#define NBLK    (NROWS / BM)   // 2048

typedef __attribute__((ext_vector_type(8))) short short8;
typedef __attribute__((ext_vector_type(4))) float f32x4;

__device__ __forceinline__ unsigned short f2bf(float f) {
    unsigned u = __float_as_uint(f);
    unsigned r = (u + 0x7FFFu + ((u >> 16) & 1u)) >> 16;
    return (unsigned short)r;
}

// LDS cell addressing: k-packed cells of 8 bf16 (16 B), cell(kg, r) for 32 rows,
// XOR-swizzled (proven R4-R13; writer+reader agree).
__device__ __forceinline__ int cellb(int kg, int r) {
    return (((kg << 5) + r) << 4) ^ ((kg & 3) << 5);
}

__device__ __forceinline__ uint4 pack8(float4 a0, float4 a1, float4 b0, float4 b1) {
    uint4 pk;
    pk.x = (unsigned)f2bf(a0.x + b0.x) | ((unsigned)f2bf(a0.y + b0.y) << 16);
    pk.y = (unsigned)f2bf(a0.z + b0.z) | ((unsigned)f2bf(a0.w + b0.w) << 16);
    pk.z = (unsigned)f2bf(a1.x + b1.x) | ((unsigned)f2bf(a1.y + b1.y) << 16);
    pk.w = (unsigned)f2bf(a1.z + b1.z) | ((unsigned)f2bf(a1.w + b1.w) << 16);
    return pk;
}

// ---------------- K0: weights -> bf16, MFMA-fragment-packed (16x16) ----------------
// Fragment order: [tile=n>>4][kt][lane][j], elem: n = tile*16+(l&15),
// k = kt*32+(l>>4)*8+j.  Same lane mapping serves as A or B operand.
__global__ void k_prep(const float* __restrict__ W1, const float* __restrict__ W2,
                       const float* __restrict__ W3,
                       unsigned short* __restrict__ w1p, unsigned short* __restrict__ w2p,
                       unsigned short* __restrict__ w3p) {
    int idx = blockIdx.x * 256 + threadIdx.x;
    if (idx < 131072) {                      // W1: K=256 (kt 0..7), N=512 (tile 0..31)
        int j = idx & 7, l = (idx >> 3) & 63, kt = (idx >> 9) & 7, tile = idx >> 12;
        int n = tile * 16 + (l & 15);
        int k = kt * 32 + (l >> 4) * 8 + j;
        w1p[idx] = f2bf(W1[k * 512 + n]);
    } else if (idx < 393216) {               // W2: K=512 (kt 0..15), N=512 (tile 0..31)
        int i2 = idx - 131072;
        int j = i2 & 7, l = (i2 >> 3) & 63, kt = (i2 >> 9) & 15, tile = i2 >> 13;
        int n = tile * 16 + (l & 15);
        int k = kt * 32 + (l >> 4) * 8 + j;
        w2p[i2] = f2bf(W2[k * 512 + n]);
    } else if (idx < 524288) {               // W3: K=512 (kt 0..15), N=256 (tile 0..15)
        int i3 = idx - 393216;
        int j = i3 & 7, l = (i3 >> 3) & 63, kt = (i3 >> 9) & 15, tile = i3 >> 13;
        int n = tile * 16 + (l & 15);
        int k = kt * 32 + (l >> 4) * 8 + j;
        w3p[i3] = f2bf(W3[k * 256 + n]);
    }
}

// ---------------- K1: fused MLP chain — EDGE-INNER + SWAPPED OPERANDS (R14) ----------------
// 2048 blocks x 512 thr (8 waves), block owns 32 batch rows.
// MFMA computes D[n][m] = W_frag x act_frag (operands SWAPPED vs R13): the
// fragment reads are byte-identical (W and act frags share the lane mapping),
// but each thread now holds 4 CONSECUTIVE n for one batch row m -> epilogue
// writes into the k-packed cells become ds_write_b64 (24+8 vs 96+32 scalar
// u16) and the z-epilogue becomes float4 stores. Biases load as float4 at
// point of use (per-reg n-bias).
// LDS map (144 KB, 1 block/CU):
//   h1s[e]  : e*32768, [0,96K) — layer1 out (h1^T cells) / layer2 B-source
//   ebuf[e] : 96K+e*16384      — staged edge inputs (layer1 B-source)
//   aggb    : 96K, 32 KB       — agg cells, reuses dead ebuf after layer1
//   zbuf    : [0,33280) fp32 [32][260] padded — reuses h1s[0..] after layer2
// amdgpu_waves_per_eu(2,2): pins allocator (R12 lesson: launch_bounds min
// alone lets it chase occupancy -> 64 regs -> 1 GB spills).
__global__ __launch_bounds__(512) __attribute__((amdgpu_waves_per_eu(2, 2)))
void k_fused(const float* __restrict__ x,
             const unsigned short* __restrict__ w1p,
             const unsigned short* __restrict__ w2p,
             const unsigned short* __restrict__ w3p,
             const float* __restrict__ b1, const float* __restrict__ b2,
             const float* __restrict__ b3,
             float* __restrict__ out,
             float* __restrict__ psum, float* __restrict__ psumsq) {
    __shared__ __align__(16) unsigned char smem[147456];
    unsigned char* h1b  = smem;             // 3 x 32 KB
    unsigned char* ebb  = smem + 98304;     // 3 x 16 KB
    unsigned char* aggb = smem + 98304;     // 32 KB (aliases ebuf0+ebuf1)
    float* zbuf = (float*)smem;             // [32][260] fp32 (aliases h1s)

    const int tid = threadIdx.x;
    const int w   = tid >> 6;
    const int l   = tid & 63;
    const int l15 = l & 15;
    const int lg  = l >> 4;
    const int blk = blockIdx.x;
    const int row0 = blk * BM;

    const int sr  = tid & 31;
    const int skg = tid >> 5;
    const float* xrow = x + (size_t)(row0 + sr) * 768;

    // ---- stage all 3 edge buffers (x loaded once per node) ----
#pragma unroll
    for (int h = 0; h < 2; ++h) {
        int kg = skg + h * 16;
        float4 n0a = *(const float4*)(xrow + kg * 8);
        float4 n0b = *(const float4*)(xrow + kg * 8 + 4);
        float4 n1a = *(const float4*)(xrow + 256 + kg * 8);
        float4 n1b = *(const float4*)(xrow + 256 + kg * 8 + 4);
        float4 n2a = *(const float4*)(xrow + 512 + kg * 8);
        float4 n2b = *(const float4*)(xrow + 512 + kg * 8 + 4);
        *(uint4*)(ebb + cellb(kg, sr))         = pack8(n0a, n0b, n1a, n1b);  // e01
        *(uint4*)(ebb + 16384 + cellb(kg, sr)) = pack8(n0a, n0b, n2a, n2b);  // e02
        *(uint4*)(ebb + 32768 + cellb(kg, sr)) = pack8(n1a, n1b, n2a, n2b);  // e12
    }

    // ---- layer1: c1[e][nt][mt] = W1 x e  (K=256, 8 kt, swapped operands) ----
    f32x4 c1[3][4][2];
#pragma unroll
    for (int e = 0; e < 3; ++e)
#pragma unroll
        for (int nt = 0; nt < 4; ++nt)
#pragma unroll
            for (int mt = 0; mt < 2; ++mt) c1[e][nt][mt] = (f32x4){0.f, 0.f, 0.f, 0.f};

    {
        short8 eP[3][2], eQ[3][2], wP[4], wQ[4];
#pragma unroll
        for (int nt = 0; nt < 4; ++nt)
            wP[nt] = *(const short8*)(w1p + (((w * 4 + nt) * 8) * 64 + l) * 8);
        __syncthreads();   // ebuf ready
#pragma unroll
        for (int e = 0; e < 3; ++e)
#pragma unroll
            for (int mt = 0; mt < 2; ++mt)
                eP[e][mt] = *(const short8*)(ebb + e * 16384 + cellb(lg, mt * 16 + l15));
#pragma unroll 1
        for (int kt = 0; kt < 8; kt += 2) {
#pragma unroll
            for (int e = 0; e < 3; ++e)
#pragma unroll
                for (int mt = 0; mt < 2; ++mt)
                    eQ[e][mt] = *(const short8*)(ebb + e * 16384 + cellb((kt + 1) * 4 + lg, mt * 16 + l15));
#pragma unroll
            for (int nt = 0; nt < 4; ++nt)
                wQ[nt] = *(const short8*)(w1p + (((w * 4 + nt) * 8 + kt + 1) * 64 + l) * 8);
            __builtin_amdgcn_s_setprio(1);
#pragma unroll
            for (int nt = 0; nt < 4; ++nt)
#pragma unroll
                for (int e = 0; e < 3; ++e)
#pragma unroll
                    for (int mt = 0; mt < 2; ++mt)
                        c1[e][nt][mt] = __builtin_amdgcn_mfma_f32_16x16x32_bf16(wP[nt], eP[e][mt], c1[e][nt][mt], 0, 0, 0);
            __builtin_amdgcn_s_setprio(0);
            if (kt + 2 < 8) {
#pragma unroll
                for (int e = 0; e < 3; ++e)
#pragma unroll
                    for (int mt = 0; mt < 2; ++mt)
                        eP[e][mt] = *(const short8*)(ebb + e * 16384 + cellb((kt + 2) * 4 + lg, mt * 16 + l15));
#pragma unroll
                for (int nt = 0; nt < 4; ++nt)
                    wP[nt] = *(const short8*)(w1p + (((w * 4 + nt) * 8 + kt + 2) * 64 + l) * 8);
            }
            __builtin_amdgcn_s_setprio(1);
#pragma unroll
            for (int nt = 0; nt < 4; ++nt)
#pragma unroll
                for (int e = 0; e < 3; ++e)
#pragma unroll
                    for (int mt = 0; mt < 2; ++mt)
                        c1[e][nt][mt] = __builtin_amdgcn_mfma_f32_16x16x32_bf16(wQ[nt], eQ[e][mt], c1[e][nt][mt], 0, 0, 0);
            __builtin_amdgcn_s_setprio(0);
        }
    }

    // ---- layer1 epilogue: relu(c1+b1) -> h1s[e] cells via ds_write_b64 ----
    // Thread holds n = w*64+nt*16+lg*4+{0..3}, m = mt*16+l15.
    {
#pragma unroll
        for (int nt = 0; nt < 4; ++nt) {
            float4 bv = *(const float4*)(b1 + w * 64 + nt * 16 + lg * 4);
            int kg = w * 8 + nt * 2 + (lg >> 1);
            int boff = (lg & 1) * 8;
#pragma unroll
            for (int e = 0; e < 3; ++e)
#pragma unroll
                for (int mt = 0; mt < 2; ++mt) {
                    float v0 = c1[e][nt][mt][0] + bv.x; v0 = v0 > 0.f ? v0 : 0.f;
                    float v1 = c1[e][nt][mt][1] + bv.y; v1 = v1 > 0.f ? v1 : 0.f;
                    float v2 = c1[e][nt][mt][2] + bv.z; v2 = v2 > 0.f ? v2 : 0.f;
                    float v3 = c1[e][nt][mt][3] + bv.w; v3 = v3 > 0.f ? v3 : 0.f;
                    uint2 pk;
                    pk.x = (unsigned)f2bf(v0) | ((unsigned)f2bf(v1) << 16);
                    pk.y = (unsigned)f2bf(v2) | ((unsigned)f2bf(v3) << 16);
                    *(uint2*)(h1b + e * 32768 + cellb(kg, mt * 16 + l15) + boff) = pk;
                }
        }
    }
    __syncthreads();   // h1s ready; ebuf reads done (aggb overwrite safe later)

    // ---- layer2: c2[e][nt][mt] = W2 x h1[e]  (K=512, 16 kt, swapped) ----
    f32x4 c2[3][4][2];
#pragma unroll
    for (int e = 0; e < 3; ++e)
#pragma unroll
        for (int nt = 0; nt < 4; ++nt)
#pragma unroll
            for (int mt = 0; mt < 2; ++mt) c2[e][nt][mt] = (f32x4){0.f, 0.f, 0.f, 0.f};

    {
        short8 hP[3][2], hQ[3][2], wP[4], wQ[4];
#pragma unroll
        for (int nt = 0; nt < 4; ++nt)
            wP[nt] = *(const short8*)(w2p + (((w * 4 + nt) * 16) * 64 + l) * 8);
#pragma unroll
        for (int e = 0; e < 3; ++e)
#pragma unroll
            for (int mt = 0; mt < 2; ++mt)
                hP[e][mt] = *(const short8*)(h1b + e * 32768 + cellb(lg, mt * 16 + l15));
#pragma unroll 1
        for (int kt = 0; kt < 16; kt += 2) {
#pragma unroll
            for (int e = 0; e < 3; ++e)
#pragma unroll
                for (int mt = 0; mt < 2; ++mt)
                    hQ[e][mt] = *(const short8*)(h1b + e * 32768 + cellb((kt + 1) * 4 + lg, mt * 16 + l15));
#pragma unroll
            for (int nt = 0; nt < 4; ++nt)
                wQ[nt] = *(const short8*)(w2p + (((w * 4 + nt) * 16 + kt + 1) * 64 + l) * 8);
            __builtin_amdgcn_s_setprio(1);
#pragma unroll
            for (int nt = 0; nt < 4; ++nt)
#pragma unroll
                for (int e = 0; e < 3; ++e)
#pragma unroll
                    for (int mt = 0; mt < 2; ++mt)
                        c2[e][nt][mt] = __builtin_amdgcn_mfma_f32_16x16x32_bf16(wP[nt], hP[e][mt], c2[e][nt][mt], 0, 0, 0);
            __builtin_amdgcn_s_setprio(0);
            if (kt + 2 < 16) {
#pragma unroll
                for (int e = 0; e < 3; ++e)
#pragma unroll
                    for (int mt = 0; mt < 2; ++mt)
                        hP[e][mt] = *(const short8*)(h1b + e * 32768 + cellb((kt + 2) * 4 + lg, mt * 16 + l15));
#pragma unroll
                for (int nt = 0; nt < 4; ++nt)
                    wP[nt] = *(const short8*)(w2p + (((w * 4 + nt) * 16 + kt + 2) * 64 + l) * 8);
            }
            __builtin_amdgcn_s_setprio(1);
#pragma unroll
            for (int nt = 0; nt < 4; ++nt)
#pragma unroll
                for (int e = 0; e < 3; ++e)
#pragma unroll
                    for (int mt = 0; mt < 2; ++mt)
                        c2[e][nt][mt] = __builtin_amdgcn_mfma_f32_16x16x32_bf16(wQ[nt], hQ[e][mt], c2[e][nt][mt], 0, 0, 0);
            __builtin_amdgcn_s_setprio(0);
        }
    }

    // ---- agg = sum_e relu(c2[e]+b2) -> aggb cells via ds_write_b64 ----
    {
#pragma unroll
        for (int nt = 0; nt < 4; ++nt) {
            float4 bv = *(const float4*)(b2 + w * 64 + nt * 16 + lg * 4);
            int kg = w * 8 + nt * 2 + (lg >> 1);
            int boff = (lg & 1) * 8;
#pragma unroll
            for (int mt = 0; mt < 2; ++mt) {
                float s0 = 0.f, s1 = 0.f, s2 = 0.f, s3 = 0.f;
#pragma unroll
                for (int e = 0; e < 3; ++e) {
                    float v0 = c2[e][nt][mt][0] + bv.x; s0 += (v0 > 0.f ? v0 : 0.f);
                    float v1 = c2[e][nt][mt][1] + bv.y; s1 += (v1 > 0.f ? v1 : 0.f);
                    float v2 = c2[e][nt][mt][2] + bv.z; s2 += (v2 > 0.f ? v2 : 0.f);
                    float v3 = c2[e][nt][mt][3] + bv.w; s3 += (v3 > 0.f ? v3 : 0.f);
                }
                uint2 pk;
                pk.x = (unsigned)f2bf(s0) | ((unsigned)f2bf(s1) << 16);
                pk.y = (unsigned)f2bf(s2) | ((unsigned)f2bf(s3) << 16);
                *(uint2*)(aggb + cellb(kg, mt * 16 + l15) + boff) = pk;
            }
        }
    }
    __syncthreads();   // aggb complete; h1s reads all done

    // ---- layer3: c3[nt][mt] = W3 x agg  (K=512, wave owns 32 n-cols, swapped) ----
    f32x4 c3[2][2];
#pragma unroll
    for (int nt = 0; nt < 2; ++nt)
#pragma unroll
        for (int mt = 0; mt < 2; ++mt) c3[nt][mt] = (f32x4){0.f, 0.f, 0.f, 0.f};

    {
        short8 aP[2], aQ[2], wP[2], wQ[2];
#pragma unroll
        for (int nt = 0; nt < 2; ++nt)
            wP[nt] = *(const short8*)(w3p + (((w * 2 + nt) * 16) * 64 + l) * 8);
#pragma unroll
        for (int mt = 0; mt < 2; ++mt)
            aP[mt] = *(const short8*)(aggb + cellb(lg, mt * 16 + l15));
#pragma unroll 1
        for (int kt = 0; kt < 16; kt += 2) {
#pragma unroll
            for (int mt = 0; mt < 2; ++mt)
                aQ[mt] = *(const short8*)(aggb + cellb((kt + 1) * 4 + lg, mt * 16 + l15));
#pragma unroll
            for (int nt = 0; nt < 2; ++nt)
                wQ[nt] = *(const short8*)(w3p + (((w * 2 + nt) * 16 + kt + 1) * 64 + l) * 8);
            __builtin_amdgcn_s_setprio(1);
#pragma unroll
            for (int nt = 0; nt < 2; ++nt)
#pragma unroll
                for (int mt = 0; mt < 2; ++mt)
                    c3[nt][mt] = __builtin_amdgcn_mfma_f32_16x16x32_bf16(wP[nt], aP[mt], c3[nt][mt], 0, 0, 0);
            __builtin_amdgcn_s_setprio(0);
            if (kt + 2 < 16) {
#pragma unroll
                for (int mt = 0; mt < 2; ++mt)
                    aP[mt] = *(const short8*)(aggb + cellb((kt + 2) * 4 + lg, mt * 16 + l15));
#pragma unroll
                for (int nt = 0; nt < 2; ++nt)
                    wP[nt] = *(const short8*)(w3p + (((w * 2 + nt) * 16 + kt + 2) * 64 + l) * 8);
            }
            __builtin_amdgcn_s_setprio(1);
#pragma unroll
            for (int nt = 0; nt < 2; ++nt)
#pragma unroll
                for (int mt = 0; mt < 2; ++mt)
                    c3[nt][mt] = __builtin_amdgcn_mfma_f32_16x16x32_bf16(wQ[nt], aQ[mt], c3[nt][mt], 0, 0, 0);
            __builtin_amdgcn_s_setprio(0);
        }
    }

    // ---- z epilogue: float4 stores into padded zbuf [32][260] + BN partials ----
    // Thread holds z cols n3 = w*32+nt*16+lg*4+{0..3} at row m = mt*16+l15.
#pragma unroll
    for (int nt = 0; nt < 2; ++nt) {
        float4 bv = *(const float4*)(b3 + w * 32 + nt * 16 + lg * 4);
        float s0 = 0.f, s1 = 0.f, s2 = 0.f, s3 = 0.f;
        float q0 = 0.f, q1 = 0.f, q2 = 0.f, q3 = 0.f;
#pragma unroll
        for (int mt = 0; mt < 2; ++mt) {
            float4 v;
            v.x = c3[nt][mt][0] + bv.x;
            v.y = c3[nt][mt][1] + bv.y;
            v.z = c3[nt][mt][2] + bv.z;
            v.w = c3[nt][mt][3] + bv.w;
            int m = mt * 16 + l15;
            *(float4*)(zbuf + m * 260 + w * 32 + nt * 16 + lg * 4) = v;
            s0 += v.x; s1 += v.y; s2 += v.z; s3 += v.w;
            q0 += v.x * v.x; q1 += v.y * v.y; q2 += v.z * v.z; q3 += v.w * v.w;
        }
        // reduce over the 16 l15-lanes (masks 1,2,4,8 permute only l15 bits)
#pragma unroll
        for (int o = 1; o <= 8; o <<= 1) {
            s0 += __shfl_xor(s0, o); s1 += __shfl_xor(s1, o);
            s2 += __shfl_xor(s2, o); s3 += __shfl_xor(s3, o);
            q0 += __shfl_xor(q0, o); q1 += __shfl_xor(q1, o);
            q2 += __shfl_xor(q2, o); q3 += __shfl_xor(q3, o);
        }
        if (l15 == 0) {
            int c = w * 32 + nt * 16 + lg * 4;
            psum[(c + 0) * NBLK + blk] = s0;
            psum[(c + 1) * NBLK + blk] = s1;
            psum[(c + 2) * NBLK + blk] = s2;
            psum[(c + 3) * NBLK + blk] = s3;
            psumsq[(c + 0) * NBLK + blk] = q0;
            psumsq[(c + 1) * NBLK + blk] = q1;
            psumsq[(c + 2) * NBLK + blk] = q2;
            psumsq[(c + 3) * NBLK + blk] = q3;
        }
    }
    __syncthreads();
    {
        const float4* zb4 = (const float4*)zbuf;
        float4* o4 = (float4*)(out + (size_t)row0 * 256);
#pragma unroll
        for (int i = 0; i < 4; ++i) {
            int idx = tid + i * 512;
            int r = idx >> 6, c4 = idx & 63;
            o4[idx] = zb4[r * 65 + c4];
        }
    }
}

// ---------------- K2: reduce 2048 partials -> scale/shift ----------------
__global__ void k_stats2(const float* __restrict__ psum, const float* __restrict__ psumsq,
                         const float* __restrict__ gamma, const float* __restrict__ beta,
                         float* __restrict__ scale, float* __restrict__ shift) {
    int f = blockIdx.x, t = threadIdx.x;
    const float* ps = psum + f * NBLK;
    const float* pq = psumsq + f * NBLK;
    float s = 0.f, q = 0.f;
#pragma unroll
    for (int i = 0; i < 8; ++i) {
        s += ps[t + i * 256];
        q += pq[t + i * 256];
    }
#pragma unroll
    for (int o = 32; o > 0; o >>= 1) {
        s += __shfl_down(s, o);
        q += __shfl_down(q, o);
    }
    __shared__ float ls[4], lq[4];
    if ((t & 63) == 0) { ls[t >> 6] = s; lq[t >> 6] = q; }
    __syncthreads();
    if (t == 0) {
        s = ls[0] + ls[1] + ls[2] + ls[3];
        q = lq[0] + lq[1] + lq[2] + lq[3];
        float mu  = s * (1.f / 65536.f);
        float var = q * (1.f / 65536.f) - mu * mu;
        float sc  = gamma[f] * rsqrtf(var + EPS);
        scale[f] = sc;
        shift[f] = beta[f] - mu * sc;
    }
}

// ---------------- K3: in-place normalize of d_out ----------------
__global__ void k_norm(float4* __restrict__ out4, const float4* __restrict__ scale4,
                       const float4* __restrict__ shift4, int n4) {
    int i = blockIdx.x * blockDim.x + threadIdx.x;
    int stride = gridDim.x * blockDim.x;
    for (; i < n4; i += stride) {
        float4 v = out4[i];
        float4 sc = scale4[i & 63];
        float4 sh = shift4[i & 63];
        v.x = v.x * sc.x + sh.x;
        v.y = v.y * sc.y + sh.y;
        v.z = v.z * sc.z + sh.z;
        v.w = v.w * sc.w + sh.w;
        out4[i] = v;
    }
}

extern "C" void kernel_launch(void* const* d_in, const int* in_sizes, int n_in,
                              void* d_out, int out_size, void* d_ws, size_t ws_size,
                              hipStream_t stream) {
    const float* x     = (const float*)d_in[0];
    const float* W1    = (const float*)d_in[1];
    const float* b1    = (const float*)d_in[2];
    const float* W2    = (const float*)d_in[3];
    const float* b2    = (const float*)d_in[4];
    const float* W3    = (const float*)d_in[5];
    const float* b3    = (const float*)d_in[6];
    const float* gamma = (const float*)d_in[7];
    const float* beta  = (const float*)d_in[8];

    char* ws = (char*)d_ws;
    unsigned short* w1p = (unsigned short*)(ws);            // 256 KB
    unsigned short* w2p = (unsigned short*)(ws + 262144);   // 512 KB
    unsigned short* w3p = (unsigned short*)(ws + 786432);   // 256 KB
    float* psum   = (float*)(ws + 1048576);                 // 2 MB
    float* psumsq = (float*)(ws + 3145728);                 // 2 MB
    float* scale  = (float*)(ws + 5242880);                 // 1 KB
    float* shift  = (float*)(ws + 5243904);                 // 1 KB

    float* out = (float*)d_out;

    k_prep<<<2048, 256, 0, stream>>>(W1, W2, W3, w1p, w2p, w3p);
    k_fused<<<NBLK, 512, 0, stream>>>(x, w1p, w2p, w3p, b1, b2, b3, out, psum, psumsq);
    k_stats2<<<256, 256, 0, stream>>>(psum, psumsq, gamma, beta, scale, shift);
    k_norm<<<2048, 256, 0, stream>>>((float4*)out, (const float4*)scale, (const float4*)shift,
                                     (NROWS * 256) / 4);
}

// Round 15
// 231.011 us; speedup vs baseline: 1.0425x; 1.0425x over previous
//
#include <hip/hip_runtime.h>
#include <hip/hip_bf16.h>
#include <stdint.h>

#define NROWS   65536
#define EPS     1e-5f
#define BM      32
#define NBLK    (NROWS / BM)   // 2048

typedef __attribute__((ext_vector_type(8))) short short8;
typedef __attribute__((ext_vector_type(4))) float f32x4;

__device__ __forceinline__ unsigned short f2bf(float f) {
    unsigned u = __float_as_uint(f);
    unsigned r = (u + 0x7FFFu + ((u >> 16) & 1u)) >> 16;
    return (unsigned short)r;
}

// one-instruction packed fp32x2 -> bf16x2 (RNE), gfx950
__device__ __forceinline__ unsigned cvtpk(float lo, float hi) {
    unsigned r;
    asm("v_cvt_pk_bf16_f32 %0, %1, %2" : "=v"(r) : "v"(lo), "v"(hi));
    return r;
}

// LDS cell addressing: k-packed cells of 8 bf16 (16 B), cell(kg, r) for 32 rows,
// XOR-swizzled (proven R4-R13; writer+reader agree).
__device__ __forceinline__ int cellb(int kg, int r) {
    return (((kg << 5) + r) << 4) ^ ((kg & 3) << 5);
}

__device__ __forceinline__ uint4 pack8(float4 a0, float4 a1, float4 b0, float4 b1) {
    uint4 pk;
    pk.x = cvtpk(a0.x + b0.x, a0.y + b0.y);
    pk.y = cvtpk(a0.z + b0.z, a0.w + b0.w);
    pk.z = cvtpk(a1.x + b1.x, a1.y + b1.y);
    pk.w = cvtpk(a1.z + b1.z, a1.w + b1.w);
    return pk;
}

// ---------------- K0: weights -> bf16, MFMA-fragment-packed (16x16) ----------------
// Fragment order: [tile=n>>4][kt][lane][j], elem: n = tile*16+(l&15),
// k = kt*32+(l>>4)*8+j.  A wave's B-load per K-step = contiguous 1 KB. (proven R4-R13)
__global__ void k_prep(const float* __restrict__ W1, const float* __restrict__ W2,
                       const float* __restrict__ W3,
                       unsigned short* __restrict__ w1p, unsigned short* __restrict__ w2p,
                       unsigned short* __restrict__ w3p) {
    int idx = blockIdx.x * 256 + threadIdx.x;
    if (idx < 131072) {                      // W1: K=256 (kt 0..7), N=512 (tile 0..31)
        int j = idx & 7, l = (idx >> 3) & 63, kt = (idx >> 9) & 7, tile = idx >> 12;
        int n = tile * 16 + (l & 15);
        int k = kt * 32 + (l >> 4) * 8 + j;
        w1p[idx] = f2bf(W1[k * 512 + n]);
    } else if (idx < 393216) {               // W2: K=512 (kt 0..15), N=512 (tile 0..31)
        int i2 = idx - 131072;
        int j = i2 & 7, l = (i2 >> 3) & 63, kt = (i2 >> 9) & 15, tile = i2 >> 13;
        int n = tile * 16 + (l & 15);
        int k = kt * 32 + (l >> 4) * 8 + j;
        w2p[i2] = f2bf(W2[k * 512 + n]);
    } else if (idx < 524288) {               // W3: K=512 (kt 0..15), N=256 (tile 0..15)
        int i3 = idx - 393216;
        int j = i3 & 7, l = (i3 >> 3) & 63, kt = (i3 >> 9) & 15, tile = i3 >> 13;
        int n = tile * 16 + (l & 15);
        int k = kt * 32 + (l >> 4) * 8 + j;
        w3p[i3] = f2bf(W3[k * 256 + n]);
    }
}

// ---------------- K1: fused MLP chain — EDGE-INNER (R13) + cvt_pk (R15) ----------------
// 2048 blocks x 512 thr (8 waves), block owns 32 batch rows.
// All 3 edges processed TOGETHER per K-step: each B-fragment feeds 3 edges x 2
// row-tiles = 24 MFMAs; W1/W2 read once per block. Barriers per pass: 4.
// R15: all fp32->bf16 conversions via v_cvt_pk_bf16_f32 (1 op / 2 values vs ~8
// for the manual RNE bit-twiddle) — staging, layer1 epilogue, agg epilogue.
// R14's swapped-operand epilogue vectorization was net-neutral (4x bank
// conflicts) — layout kept as R13, scalar u16 h1 writes retained.
// LDS map (144 KB, 1 block/CU):
//   h1s[e]  : e*32768,      [0, 96K)
//   ebuf[e] : 96K + e*16384 [96K,144K)
//   aggb    : 96K, 32 KB (aliases dead ebuf after layer1)
//   zbuf    : [0, 32K) fp32 (aliases h1s[0] after layer2)
// amdgpu_waves_per_eu(2,2) pins 2 waves/EU -> 256-VGPR cap AND stops the
// allocator's occupancy-greed (R12: launch_bounds min alone -> 64 regs -> 1 GB
// spills). Do not replace with __launch_bounds__ arg2.
__global__ __launch_bounds__(512) __attribute__((amdgpu_waves_per_eu(2, 2)))
void k_fused(const float* __restrict__ x,
             const unsigned short* __restrict__ w1p,
             const unsigned short* __restrict__ w2p,
             const unsigned short* __restrict__ w3p,
             const float* __restrict__ b1, const float* __restrict__ b2,
             const float* __restrict__ b3,
             float* __restrict__ out,
             float* __restrict__ psum, float* __restrict__ psumsq) {
    __shared__ __align__(16) unsigned char smem[147456];
    unsigned char* h1b  = smem;             // 3 x 32 KB
    unsigned char* ebb  = smem + 98304;     // 3 x 16 KB
    unsigned char* aggb = smem + 98304;     // 32 KB (aliases ebuf0+ebuf1)
    float* zbuf = (float*)smem;             // 32 KB (aliases h1s[0])

    const int tid = threadIdx.x;
    const int w   = tid >> 6;
    const int l   = tid & 63;
    const int l15 = l & 15;
    const int lg  = l >> 4;
    const int blk = blockIdx.x;
    const int row0 = blk * BM;

    const int sr  = tid & 31;
    const int skg = tid >> 5;
    const float* xrow = x + (size_t)(row0 + sr) * 768;

    float bias1[4], bias2[4];
#pragma unroll
    for (int nt = 0; nt < 4; ++nt) {
        bias1[nt] = b1[w * 64 + nt * 16 + l15];
        bias2[nt] = b2[w * 64 + nt * 16 + l15];
    }
    float bias3[2];
#pragma unroll
    for (int nt = 0; nt < 2; ++nt) bias3[nt] = b3[w * 32 + nt * 16 + l15];

    // ---- stage all 3 edge buffers (x loaded once per node) ----
#pragma unroll
    for (int h = 0; h < 2; ++h) {
        int kg = skg + h * 16;
        float4 n0a = *(const float4*)(xrow + kg * 8);
        float4 n0b = *(const float4*)(xrow + kg * 8 + 4);
        float4 n1a = *(const float4*)(xrow + 256 + kg * 8);
        float4 n1b = *(const float4*)(xrow + 256 + kg * 8 + 4);
        float4 n2a = *(const float4*)(xrow + 512 + kg * 8);
        float4 n2b = *(const float4*)(xrow + 512 + kg * 8 + 4);
        *(uint4*)(ebb + cellb(kg, sr))         = pack8(n0a, n0b, n1a, n1b);  // e01
        *(uint4*)(ebb + 16384 + cellb(kg, sr)) = pack8(n0a, n0b, n2a, n2b);  // e02
        *(uint4*)(ebb + 32768 + cellb(kg, sr)) = pack8(n1a, n1b, n2a, n2b);  // e12
    }

    // ---- layer1: c1[e] = e @ W1  (K=256, 8 kt, B shared across 3 edges) ----
    f32x4 c1[3][2][4];
#pragma unroll
    for (int e = 0; e < 3; ++e)
#pragma unroll
        for (int mt = 0; mt < 2; ++mt)
#pragma unroll
            for (int nt = 0; nt < 4; ++nt) c1[e][mt][nt] = (f32x4){0.f, 0.f, 0.f, 0.f};

    {
        short8 aP[3][2], aQ[3][2], bP[4], bQ[4];
#pragma unroll
        for (int nt = 0; nt < 4; ++nt)
            bP[nt] = *(const short8*)(w1p + (((w * 4 + nt) * 8) * 64 + l) * 8);
        __syncthreads();   // ebuf ready
#pragma unroll
        for (int e = 0; e < 3; ++e)
#pragma unroll
            for (int mt = 0; mt < 2; ++mt)
                aP[e][mt] = *(const short8*)(ebb + e * 16384 + cellb(lg, mt * 16 + l15));
#pragma unroll 1
        for (int kt = 0; kt < 8; kt += 2) {
#pragma unroll
            for (int e = 0; e < 3; ++e)
#pragma unroll
                for (int mt = 0; mt < 2; ++mt)
                    aQ[e][mt] = *(const short8*)(ebb + e * 16384 + cellb((kt + 1) * 4 + lg, mt * 16 + l15));
#pragma unroll
            for (int nt = 0; nt < 4; ++nt)
                bQ[nt] = *(const short8*)(w1p + (((w * 4 + nt) * 8 + kt + 1) * 64 + l) * 8);
            __builtin_amdgcn_s_setprio(1);
#pragma unroll
            for (int nt = 0; nt < 4; ++nt)
#pragma unroll
                for (int e = 0; e < 3; ++e)
#pragma unroll
                    for (int mt = 0; mt < 2; ++mt)
                        c1[e][mt][nt] = __builtin_amdgcn_mfma_f32_16x16x32_bf16(aP[e][mt], bP[nt], c1[e][mt][nt], 0, 0, 0);
            __builtin_amdgcn_s_setprio(0);
            if (kt + 2 < 8) {
#pragma unroll
                for (int e = 0; e < 3; ++e)
#pragma unroll
                    for (int mt = 0; mt < 2; ++mt)
                        aP[e][mt] = *(const short8*)(ebb + e * 16384 + cellb((kt + 2) * 4 + lg, mt * 16 + l15));
#pragma unroll
                for (int nt = 0; nt < 4; ++nt)
                    bP[nt] = *(const short8*)(w1p + (((w * 4 + nt) * 8 + kt + 2) * 64 + l) * 8);
            }
            __builtin_amdgcn_s_setprio(1);
#pragma unroll
            for (int nt = 0; nt < 4; ++nt)
#pragma unroll
                for (int e = 0; e < 3; ++e)
#pragma unroll
                    for (int mt = 0; mt < 2; ++mt)
                        c1[e][mt][nt] = __builtin_amdgcn_mfma_f32_16x16x32_bf16(aQ[e][mt], bQ[nt], c1[e][mt][nt], 0, 0, 0);
            __builtin_amdgcn_s_setprio(0);
        }
    }

    // ---- layer1 epilogue: relu(c1+b1) -> h1s[e] (cvt_pk pairs, u16 lo/hi stores) ----
#pragma unroll
    for (int e = 0; e < 3; ++e)
#pragma unroll
        for (int nt = 0; nt < 4; ++nt) {
            int c = w * 64 + nt * 16 + l15;
            int cb = ((c & 7) << 1);
            unsigned char* base = h1b + e * 32768;
#pragma unroll
            for (int mt = 0; mt < 2; ++mt) {
                int r0 = mt * 16 + lg * 4;
                float v0 = fmaxf(c1[e][mt][nt][0] + bias1[nt], 0.f);
                float v1 = fmaxf(c1[e][mt][nt][1] + bias1[nt], 0.f);
                float v2 = fmaxf(c1[e][mt][nt][2] + bias1[nt], 0.f);
                float v3 = fmaxf(c1[e][mt][nt][3] + bias1[nt], 0.f);
                unsigned p01 = cvtpk(v0, v1);
                unsigned p23 = cvtpk(v2, v3);
                *(unsigned short*)(base + cellb(c >> 3, r0 + 0) + cb) = (unsigned short)p01;
                *(unsigned short*)(base + cellb(c >> 3, r0 + 1) + cb) = (unsigned short)(p01 >> 16);
                *(unsigned short*)(base + cellb(c >> 3, r0 + 2) + cb) = (unsigned short)p23;
                *(unsigned short*)(base + cellb(c >> 3, r0 + 3) + cb) = (unsigned short)(p23 >> 16);
            }
        }
    __syncthreads();   // h1s ready; ebuf reads done (aggb overwrite safe later)

    // ---- layer2: c2[e] = h1[e] @ W2  (K=512, 16 kt, B shared across edges) ----
    f32x4 c2[3][2][4];
#pragma unroll
    for (int e = 0; e < 3; ++e)
#pragma unroll
        for (int mt = 0; mt < 2; ++mt)
#pragma unroll
            for (int nt = 0; nt < 4; ++nt) c2[e][mt][nt] = (f32x4){0.f, 0.f, 0.f, 0.f};

    {
        short8 aP[3][2], aQ[3][2], bP[4], bQ[4];
#pragma unroll
        for (int nt = 0; nt < 4; ++nt)
            bP[nt] = *(const short8*)(w2p + (((w * 4 + nt) * 16) * 64 + l) * 8);
#pragma unroll
        for (int e = 0; e < 3; ++e)
#pragma unroll
            for (int mt = 0; mt < 2; ++mt)
                aP[e][mt] = *(const short8*)(h1b + e * 32768 + cellb(lg, mt * 16 + l15));
#pragma unroll 1
        for (int kt = 0; kt < 16; kt += 2) {
#pragma unroll
            for (int e = 0; e < 3; ++e)
#pragma unroll
                for (int mt = 0; mt < 2; ++mt)
                    aQ[e][mt] = *(const short8*)(h1b + e * 32768 + cellb((kt + 1) * 4 + lg, mt * 16 + l15));
#pragma unroll
            for (int nt = 0; nt < 4; ++nt)
                bQ[nt] = *(const short8*)(w2p + (((w * 4 + nt) * 16 + kt + 1) * 64 + l) * 8);
            __builtin_amdgcn_s_setprio(1);
#pragma unroll
            for (int nt = 0; nt < 4; ++nt)
#pragma unroll
                for (int e = 0; e < 3; ++e)
#pragma unroll
                    for (int mt = 0; mt < 2; ++mt)
                        c2[e][mt][nt] = __builtin_amdgcn_mfma_f32_16x16x32_bf16(aP[e][mt], bP[nt], c2[e][mt][nt], 0, 0, 0);
            __builtin_amdgcn_s_setprio(0);
            if (kt + 2 < 16) {
#pragma unroll
                for (int e = 0; e < 3; ++e)
#pragma unroll
                    for (int mt = 0; mt < 2; ++mt)
                        aP[e][mt] = *(const short8*)(h1b + e * 32768 + cellb((kt + 2) * 4 + lg, mt * 16 + l15));
#pragma unroll
                for (int nt = 0; nt < 4; ++nt)
                    bP[nt] = *(const short8*)(w2p + (((w * 4 + nt) * 16 + kt + 2) * 64 + l) * 8);
            }
            __builtin_amdgcn_s_setprio(1);
#pragma unroll
            for (int nt = 0; nt < 4; ++nt)
#pragma unroll
                for (int e = 0; e < 3; ++e)
#pragma unroll
                    for (int mt = 0; mt < 2; ++mt)
                        c2[e][mt][nt] = __builtin_amdgcn_mfma_f32_16x16x32_bf16(aQ[e][mt], bQ[nt], c2[e][mt][nt], 0, 0, 0);
            __builtin_amdgcn_s_setprio(0);
        }
    }

    // ---- agg = sum_e relu(c2[e]+b2) -> aggb (cvt_pk pairs, u16 lo/hi stores) ----
#pragma unroll
    for (int nt = 0; nt < 4; ++nt) {
        int c = w * 64 + nt * 16 + l15;
        int cb = ((c & 7) << 1);
#pragma unroll
        for (int mt = 0; mt < 2; ++mt) {
            int r0 = mt * 16 + lg * 4;
            float s0 = 0.f, s1 = 0.f, s2 = 0.f, s3 = 0.f;
#pragma unroll
            for (int e = 0; e < 3; ++e) {
                s0 += fmaxf(c2[e][mt][nt][0] + bias2[nt], 0.f);
                s1 += fmaxf(c2[e][mt][nt][1] + bias2[nt], 0.f);
                s2 += fmaxf(c2[e][mt][nt][2] + bias2[nt], 0.f);
                s3 += fmaxf(c2[e][mt][nt][3] + bias2[nt], 0.f);
            }
            unsigned p01 = cvtpk(s0, s1);
            unsigned p23 = cvtpk(s2, s3);
            *(unsigned short*)(aggb + cellb(c >> 3, r0 + 0) + cb) = (unsigned short)p01;
            *(unsigned short*)(aggb + cellb(c >> 3, r0 + 1) + cb) = (unsigned short)(p01 >> 16);
            *(unsigned short*)(aggb + cellb(c >> 3, r0 + 2) + cb) = (unsigned short)p23;
            *(unsigned short*)(aggb + cellb(c >> 3, r0 + 3) + cb) = (unsigned short)(p23 >> 16);
        }
    }
    __syncthreads();   // aggb complete; h1s reads all done

    // ---- layer3: z = agg @ W3 + b3  (K=512, wave owns 32 cols, ping-pong) ----
    f32x4 c3[2][2];
#pragma unroll
    for (int mt = 0; mt < 2; ++mt)
#pragma unroll
        for (int nt = 0; nt < 2; ++nt) c3[mt][nt] = (f32x4){0.f, 0.f, 0.f, 0.f};

    {
        short8 aP[2], aQ[2], bP[2], bQ[2];
#pragma unroll
        for (int nt = 0; nt < 2; ++nt)
            bP[nt] = *(const short8*)(w3p + (((w * 2 + nt) * 16) * 64 + l) * 8);
#pragma unroll
        for (int mt = 0; mt < 2; ++mt)
            aP[mt] = *(const short8*)(aggb + cellb(lg, mt * 16 + l15));
#pragma unroll 1
        for (int kt = 0; kt < 16; kt += 2) {
#pragma unroll
            for (int mt = 0; mt < 2; ++mt)
                aQ[mt] = *(const short8*)(aggb + cellb((kt + 1) * 4 + lg, mt * 16 + l15));
#pragma unroll
            for (int nt = 0; nt < 2; ++nt)
                bQ[nt] = *(const short8*)(w3p + (((w * 2 + nt) * 16 + kt + 1) * 64 + l) * 8);
            __builtin_amdgcn_s_setprio(1);
#pragma unroll
            for (int nt = 0; nt < 2; ++nt)
#pragma unroll
                for (int mt = 0; mt < 2; ++mt)
                    c3[mt][nt] = __builtin_amdgcn_mfma_f32_16x16x32_bf16(aP[mt], bP[nt], c3[mt][nt], 0, 0, 0);
            __builtin_amdgcn_s_setprio(0);
            if (kt + 2 < 16) {
#pragma unroll
                for (int mt = 0; mt < 2; ++mt)
                    aP[mt] = *(const short8*)(aggb + cellb((kt + 2) * 4 + lg, mt * 16 + l15));
#pragma unroll
                for (int nt = 0; nt < 2; ++nt)
                    bP[nt] = *(const short8*)(w3p + (((w * 2 + nt) * 16 + kt + 2) * 64 + l) * 8);
            }
            __builtin_amdgcn_s_setprio(1);
#pragma unroll
            for (int nt = 0; nt < 2; ++nt)
#pragma unroll
                for (int mt = 0; mt < 2; ++mt)
                    c3[mt][nt] = __builtin_amdgcn_mfma_f32_16x16x32_bf16(aQ[mt], bQ[nt], c3[mt][nt], 0, 0, 0);
            __builtin_amdgcn_s_setprio(0);
        }
    }

    // ---- z epilogue: zbuf (h1s[0] region — disjoint from aggb) + BN partials ----
#pragma unroll
    for (int nt = 0; nt < 2; ++nt) {
        int c = w * 32 + nt * 16 + l15;
        float s = 0.f, q = 0.f;
#pragma unroll
        for (int mt = 0; mt < 2; ++mt)
#pragma unroll
            for (int reg = 0; reg < 4; ++reg) {
                int r = mt * 16 + lg * 4 + reg;
                float v = c3[mt][nt][reg] + bias3[nt];
                zbuf[r * 256 + c] = v;
                s += v;
                q += v * v;
            }
        s += __shfl_xor(s, 16); s += __shfl_xor(s, 32);
        q += __shfl_xor(q, 16); q += __shfl_xor(q, 32);
        if (lg == 0) {
            psum[c * NBLK + blk] = s;
            psumsq[c * NBLK + blk] = q;
        }
    }
    __syncthreads();
    {
        const float4* zb4 = (const float4*)zbuf;
        float4* o4 = (float4*)(out + (size_t)row0 * 256);
#pragma unroll
        for (int i = 0; i < 4; ++i)
            o4[tid + i * 512] = zb4[tid + i * 512];
    }
}

// ---------------- K2: reduce 2048 partials -> scale/shift ----------------
__global__ void k_stats2(const float* __restrict__ psum, const float* __restrict__ psumsq,
                         const float* __restrict__ gamma, const float* __restrict__ beta,
                         float* __restrict__ scale, float* __restrict__ shift) {
    int f = blockIdx.x, t = threadIdx.x;
    const float* ps = psum + f * NBLK;
    const float* pq = psumsq + f * NBLK;
    float s = 0.f, q = 0.f;
#pragma unroll
    for (int i = 0; i < 8; ++i) {
        s += ps[t + i * 256];
        q += pq[t + i * 256];
    }
#pragma unroll
    for (int o = 32; o > 0; o >>= 1) {
        s += __shfl_down(s, o);
        q += __shfl_down(q, o);
    }
    __shared__ float ls[4], lq[4];
    if ((t & 63) == 0) { ls[t >> 6] = s; lq[t >> 6] = q; }
    __syncthreads();
    if (t == 0) {
        s = ls[0] + ls[1] + ls[2] + ls[3];
        q = lq[0] + lq[1] + lq[2] + lq[3];
        float mu  = s * (1.f / 65536.f);
        float var = q * (1.f / 65536.f) - mu * mu;
        float sc  = gamma[f] * rsqrtf(var + EPS);
        scale[f] = sc;
        shift[f] = beta[f] - mu * sc;
    }
}

// ---------------- K3: in-place normalize of d_out ----------------
__global__ void k_norm(float4* __restrict__ out4, const float4* __restrict__ scale4,
                       const float4* __restrict__ shift4, int n4) {
    int i = blockIdx.x * blockDim.x + threadIdx.x;
    int stride = gridDim.x * blockDim.x;
    for (; i < n4; i += stride) {
        float4 v = out4[i];
        float4 sc = scale4[i & 63];
        float4 sh = shift4[i & 63];
        v.x = v.x * sc.x + sh.x;
        v.y = v.y * sc.y + sh.y;
        v.z = v.z * sc.z + sh.z;
        v.w = v.w * sc.w + sh.w;
        out4[i] = v;
    }
}

extern "C" void kernel_launch(void* const* d_in, const int* in_sizes, int n_in,
                              void* d_out, int out_size, void* d_ws, size_t ws_size,
                              hipStream_t stream) {
    const float* x     = (const float*)d_in[0];
    const float* W1    = (const float*)d_in[1];
    const float* b1    = (const float*)d_in[2];
    const float* W2    = (const float*)d_in[3];
    const float* b2    = (const float*)d_in[4];
    const float* W3    = (const float*)d_in[5];
    const float* b3    = (const float*)d_in[6];
    const float* gamma = (const float*)d_in[7];
    const float* beta  = (const float*)d_in[8];

    char* ws = (char*)d_ws;
    unsigned short* w1p = (unsigned short*)(ws);            // 256 KB
    unsigned short* w2p = (unsigned short*)(ws + 262144);   // 512 KB
    unsigned short* w3p = (unsigned short*)(ws + 786432);   // 256 KB
    float* psum   = (float*)(ws + 1048576);                 // 2 MB
    float* psumsq = (float*)(ws + 3145728);                 // 2 MB
    float* scale  = (float*)(ws + 5242880);                 // 1 KB
    float* shift  = (float*)(ws + 5243904);                 // 1 KB

    float* out = (float*)d_out;

    k_prep<<<2048, 256, 0, stream>>>(W1, W2, W3, w1p, w2p, w3p);
    k_fused<<<NBLK, 512, 0, stream>>>(x, w1p, w2p, w3p, b1, b2, b3, out, psum, psumsq);
    k_stats2<<<256, 256, 0, stream>>>(psum, psumsq, gamma, beta, scale, shift);
    k_norm<<<2048, 256, 0, stream>>>((float4*)out, (const float4*)scale, (const float4*)shift,
                                     (NROWS * 256) / 4);
}